// Round 14
// baseline (42.552 us; speedup 1.0000x reference)
//
#include <hip/hip_runtime.h>
#include <hip/hip_bf16.h>
#include <string.h>

// PGExplainer fused edge-MLP — round 14: 2-dispatch structure.
//
// inputs (d_in order): embeds[N,128] f32, W1[384,64] f32, b1[64] f32,
//   W2[64,1] f32, b2[1] f32, u[E,1] f32, src[E] i32, dst[E] i32, n[1] i32
// out: mask[E] f32
//
// h = relu(embeds[src]@W1a + embeds[dst]@W1b + (embeds[n]@W1c + b1))
// sw = h@W2 + b2;  mask = sigmoid((gumbel(u) + sw)/TEMP)
//
// P[node][128] (1B e5m2 = f16 top byte): cols 0..63 = @W1a, 64..127 = @W1b.
// K1 pg_nodes_fused: each block rebuilds the W-fragment table in its own LDS
//   (prep kernel eliminated); last block computes cnw/cnode tables.
// K2 pg_edge: quad (4 lanes) per edge, 2 edges/quad (R10-proven).
// Theory under test: ~8-10us per dispatch of fixed overhead; 3->2 dispatches.

#define D 128
#define HID 64

typedef __attribute__((ext_vector_type(8))) short short8;
typedef __attribute__((ext_vector_type(4))) float f32x4;
typedef _Float16 h2 __attribute__((ext_vector_type(2)));

union U32H2 { unsigned u; h2 h; };

__device__ inline unsigned short f2bf(float f) {
    union { float f; unsigned int u; } x;
    x.f = f;
    unsigned int r = x.u + 0x7FFFu + ((x.u >> 16) & 1u);   // RNE
    return (unsigned short)(r >> 16);
}

__device__ inline unsigned packh(float lo, float hi) {
    _Float16 l = (_Float16)lo, h = (_Float16)hi;
    unsigned short ul, uh;
    __builtin_memcpy(&ul, &l, 2);
    __builtin_memcpy(&uh, &h, 2);
    return (unsigned)ul | ((unsigned)uh << 16);
}

__device__ inline h2 relu2(h2 x) {
#if __has_builtin(__builtin_elementwise_max)
    return __builtin_elementwise_max(x, (h2)((_Float16)0));
#else
    h2 r;
    r[0] = x[0] > (_Float16)0 ? x[0] : (_Float16)0;
    r[1] = x[1] > (_Float16)0 ? x[1] : (_Float16)0;
    return r;
#endif
}

__device__ inline float dot2acc(h2 a, h2 b, float c) {
#if __has_builtin(__builtin_amdgcn_fdot2)
    return __builtin_amdgcn_fdot2(a, b, c, false);
#else
    c = fmaf((float)a[0], (float)b[0], c);
    return fmaf((float)a[1], (float)b[1], c);
#endif
}

// pack 2 f32 -> u32 of f16x2 via cvt_pkrtz (bit-copy avoids fp16 type clash)
__device__ inline unsigned pkrtz_u32(float a, float b) {
    auto v = __builtin_amdgcn_cvt_pkrtz(a, b);
    unsigned u;
    __builtin_memcpy(&u, &v, 4);
    return u;
}

// --- K1: node projections via MFMA (per-block LDS W-frag table) ---
// Last block instead computes the packed cnode/W2 pair table cnw.
__global__ __launch_bounds__(256) void pg_nodes_fused(
    const float* __restrict__ embeds, const float* __restrict__ W1,
    const float* __restrict__ b1, const float* __restrict__ W2,
    const int* __restrict__ nidx, unsigned* __restrict__ cnw,
    unsigned char* __restrict__ P, int N, int NTILES)
{
    int t = threadIdx.x;

    if (blockIdx.x == gridDim.x - 1) {
        // cnw[r*16 + q] = f16pair(cs[j], cs[j+2]); j = 4*(t>>1)+(t&1) per R12
        __shared__ float cs[HID];
        if (t < HID) {
            int n = nidx[0];
            const float* nr = embeds + (size_t)n * D;
            float c = b1[t];
            #pragma unroll 8
            for (int k = 0; k < D; ++k)
                c = fmaf(nr[k], W1[(2 * D + k) * HID + t], c);
            cs[t] = c;
        }
        __syncthreads();
        if (t < 32) {
            int wi = t >> 1, sub = t & 1;
            int j = 4 * wi + sub;                  // units (j, j+2)
            int r = t >> 3, q = t & 7;
            cnw[r * 16 + q]     = packh(cs[j], cs[j + 2]);
            cnw[r * 16 + 8 + q] = packh(W2[j], W2[j + 2]);
        }
        return;
    }

    __shared__ unsigned short wl[16384];              // 32 KiB W-frag table
    __shared__ unsigned char st[4][16 * 144];         // 9 KiB store staging

    // build fragment-ordered W table in LDS (was the separate prep kernel):
    // wl[((ks*8+ct)*64+lane)*8+j] = Wcomb[ks*32+(lane>>4)*8+j][ct*16+(lane&15)]
    #pragma unroll 4
    for (int it = 0; it < 64; ++it) {
        int i    = it * 256 + t;
        int j    = i & 7;
        int lane = (i >> 3) & 63;
        int ct   = (i >> 9) & 7;
        int ks   = i >> 12;
        int k    = ks * 32 + (lane >> 4) * 8 + j;
        int col  = ct * 16 + (lane & 15);
        float w  = (col < HID) ? W1[k * HID + col]
                               : W1[(D + k) * HID + (col - HID)];
        wl[i] = f2bf(w);
    }
    __syncthreads();

    int wave  = t >> 6;
    int lane  = t & 63;
    int ntile = blockIdx.x * 4 + wave;
    if (ntile >= NTILES) return;

    int kg = lane >> 4;                               // 0..3 k-group
    int nr = ntile * 16 + (lane & 15);                // node (B-operand col)
    if (nr >= N) nr = N - 1;
    const float* row = embeds + (size_t)nr * D + kg * 8;

    short8 af[4];
    #pragma unroll
    for (int ks = 0; ks < 4; ++ks) {
        float4 v0 = *reinterpret_cast<const float4*>(row + ks * 32);
        float4 v1 = *reinterpret_cast<const float4*>(row + ks * 32 + 4);
        union { float f; unsigned u; } c[8];
        c[0].f = v0.x; c[1].f = v0.y; c[2].f = v0.z; c[3].f = v0.w;
        c[4].f = v1.x; c[5].f = v1.y; c[6].f = v1.z; c[7].f = v1.w;
        union { unsigned u[4]; short8 s; } pk;
        #pragma unroll
        for (int p = 0; p < 4; ++p)                   // truncate-pack 2 f32 -> u32
            pk.u[p] = (c[2 * p + 1].u & 0xFFFF0000u) | (c[2 * p].u >> 16);
        af[ks] = pk.s;
    }

    const short8* wl8 = reinterpret_cast<const short8*>(wl);

    f32x4 acc[8];
    #pragma unroll
    for (int ct = 0; ct < 8; ++ct) acc[ct] = (f32x4){0.f, 0.f, 0.f, 0.f};

    // SWAPPED operands: D = W^T_tile * emb^T_tile -> D[wcol][node]
    #pragma unroll
    for (int ct = 0; ct < 8; ++ct) {
        #pragma unroll
        for (int ks = 0; ks < 4; ++ks) {
            short8 wf = wl8[(ks * 8 + ct) * 64 + lane];
            acc[ct] = __builtin_amdgcn_mfma_f32_16x16x32_bf16(wf, af[ks], acc[ct], 0, 0, 0);
        }
    }

    // e5m2 pack: cvt_pkrtz, RNE-to-top-byte adjust, v_perm
    #pragma unroll
    for (int ct = 0; ct < 8; ++ct) {
        unsigned p0 = pkrtz_u32(acc[ct][0], acc[ct][1]);
        unsigned p1 = pkrtz_u32(acc[ct][2], acc[ct][3]);
        unsigned u0 = p0 + 0x007F007Fu + ((p0 >> 8) & 0x00010001u);
        unsigned u1 = p1 + 0x007F007Fu + ((p1 >> 8) & 0x00010001u);
        unsigned w = __builtin_amdgcn_perm(u1, u0, 0x07050301u); // hi-bytes of 4 f16
        *reinterpret_cast<unsigned*>(&st[wave][(lane & 15) * 144 + ct * 16 + kg * 4]) = w;
    }
    // same-wave LDS RAW -> compiler inserts lgkmcnt wait; no barrier needed
    #pragma unroll
    for (int h = 0; h < 2; ++h) {
        int c   = lane + h * 64;
        int r   = c >> 3;                              // 0..15
        int off = (c & 7) * 16;                        // 0..112
        uint4 v = *reinterpret_cast<const uint4*>(&st[wave][r * 144 + off]);
        int node = ntile * 16 + r;
        if (node < N)
            *reinterpret_cast<uint4*>(P + (size_t)node * 128 + off) = v;
    }
}

// 16-unit partial MLP (lane covers units 16r..16r+15); no bias here.
__device__ inline float mlp16(uint4 A, uint4 B,
                              const unsigned* cn, const unsigned* w2)
{
    float sw = 0.f;
    unsigned aw[4] = {A.x, A.y, A.z, A.w};
    unsigned bw[4] = {B.x, B.y, B.z, B.w};
    #pragma unroll
    for (int w = 0; w < 4; ++w) {
        U32H2 a0, a1, b0, b1, c0, c1, W0, W1v;
        a0.u = (aw[w] << 8) & 0xFF00FF00u;
        a1.u =  aw[w]       & 0xFF00FF00u;
        b0.u = (bw[w] << 8) & 0xFF00FF00u;
        b1.u =  bw[w]       & 0xFF00FF00u;
        c0.u = cn[2 * w];  c1.u = cn[2 * w + 1];
        W0.u = w2[2 * w];  W1v.u = w2[2 * w + 1];
        h2 h0 = relu2(a0.h + b0.h + c0.h);
        h2 h1 = relu2(a1.h + b1.h + c1.h);
        sw = dot2acc(h0, W0.h, sw);
        sw = dot2acc(h1, W1v.h, sw);
    }
    return sw;
}

__device__ inline float gumbel_sigmoid(float uu, float sw) {
    float a = 0.9999f - 0.9998f * uu;                  // eps
    float b = 0.0001f + 0.9998f * uu;                  // 1-eps
    float gate = __logf(__fdividef(a, b));
    float x = (gate + sw) * 0.2f;                      // / TEMP
    return __fdividef(1.f, 1.f + __expf(-x));
}

// --- K2: quad (4 lanes) per edge, 2 edges per quad (R10-proven) ---
__global__ __launch_bounds__(256) void pg_edge(
    const unsigned char* __restrict__ P, const uint4* __restrict__ cnw4,
    const float* __restrict__ b2, const float* __restrict__ u,
    const int* __restrict__ src, const int* __restrict__ dst,
    float* __restrict__ out, int E)
{
    int r    = threadIdx.x & 3;                        // lane-in-quad
    int quad = (blockIdx.x * 256 + threadIdx.x) >> 2;  // global quad
    int e0   = quad * 2;
    if (e0 >= E) return;
    bool two = (e0 + 1 < E);

    // constants: one 64B line per lane (4x uint4, broadcast within r-group)
    uint4 c0 = cnw4[r * 4 + 0], c1 = cnw4[r * 4 + 1];
    uint4 c2 = cnw4[r * 4 + 2], c3 = cnw4[r * 4 + 3];
    unsigned cn[8] = {c0.x, c0.y, c0.z, c0.w, c1.x, c1.y, c1.z, c1.w};
    unsigned w2[8] = {c2.x, c2.y, c2.z, c2.w, c3.x, c3.y, c3.z, c3.w};

    int2 sv, dv;
    if (two) {
        sv = *reinterpret_cast<const int2*>(src + e0);
        dv = *reinterpret_cast<const int2*>(dst + e0);
    } else {
        sv.x = sv.y = src[e0];
        dv.x = dv.y = dst[e0];
    }

    // quad-cooperative row loads: lanes r=0..3 -> consecutive 16B chunks
    uint4 A0 = *reinterpret_cast<const uint4*>(P + (size_t)sv.x * 128 + r * 16);
    uint4 B0 = *reinterpret_cast<const uint4*>(P + (size_t)dv.x * 128 + 64 + r * 16);
    uint4 A1 = *reinterpret_cast<const uint4*>(P + (size_t)sv.y * 128 + r * 16);
    uint4 B1 = *reinterpret_cast<const uint4*>(P + (size_t)dv.y * 128 + 64 + r * 16);

    float sw0 = mlp16(A0, B0, cn, w2);
    float sw1 = mlp16(A1, B1, cn, w2);

    sw0 += __shfl_xor(sw0, 1); sw0 += __shfl_xor(sw0, 2);
    sw1 += __shfl_xor(sw1, 1); sw1 += __shfl_xor(sw1, 2);

    if (r == 0) {
        float bb = b2[0];
        if (two) {
            float2 uv = *reinterpret_cast<const float2*>(u + e0);
            float2 o;
            o.x = gumbel_sigmoid(uv.x, sw0 + bb);
            o.y = gumbel_sigmoid(uv.y, sw1 + bb);
            *reinterpret_cast<float2*>(out + e0) = o;
        } else {
            out[e0] = gumbel_sigmoid(u[e0], sw0 + bb);
        }
    }
}

extern "C" void kernel_launch(void* const* d_in, const int* in_sizes, int n_in,
                              void* d_out, int out_size, void* d_ws, size_t ws_size,
                              hipStream_t stream) {
    const float* embeds = (const float*)d_in[0];
    const float* W1     = (const float*)d_in[1];
    const float* b1     = (const float*)d_in[2];
    const float* W2     = (const float*)d_in[3];
    const float* b2     = (const float*)d_in[4];
    const float* u      = (const float*)d_in[5];
    const int*   src    = (const int*)d_in[6];
    const int*   dst    = (const int*)d_in[7];
    const int*   nidx   = (const int*)d_in[8];

    int E = in_sizes[6];
    int N = in_sizes[0] / D;
    int NTILES = (N + 15) / 16;

    // ws: cnw 64 u32 (256B) | P [N][128] u8 (6.4MB)
    unsigned* cnw = (unsigned*)d_ws;
    unsigned char* P = (unsigned char*)(cnw + 64);

    int nb = (NTILES + 3) / 4 + 1;                    // +1 block for cnw/cnode
    pg_nodes_fused<<<nb, 256, 0, stream>>>(embeds, W1, b1, W2, nidx, cnw, P,
                                           N, NTILES);

    long quads = ((long)E + 1) / 2;                   // 2 edges per quad
    int blocks = (int)((quads * 4 + 255) / 256);
    pg_edge<<<blocks, 256, 0, stream>>>(P, (const uint4*)cnw, b2, u,
                                        src, dst, (float*)d_out, E);
}

// Round 16
// 36.781 us; speedup vs baseline: 1.1569x; 1.1569x over previous
//
#include <hip/hip_runtime.h>
#include <hip/hip_bf16.h>
#include <string.h>

// PGExplainer fused edge-MLP — round 16: R10 structure + NONTEMPORAL
//   producer stores (bfrag/cnw/P) — compile fix (ext_vector for nt-store).
//
// inputs (d_in order): embeds[N,128] f32, W1[384,64] f32, b1[64] f32,
//   W2[64,1] f32, b2[1] f32, u[E,1] f32, src[E] i32, dst[E] i32, n[1] i32
// out: mask[E] f32
//
// h = relu(embeds[src]@W1a + embeds[dst]@W1b + (embeds[n]@W1c + b1))
// sw = h@W2 + b2;  mask = sigmoid((gumbel(u) + sw)/TEMP)
//
// P[node][128] (1B e5m2 = f16 top byte): cols 0..63 = @W1a, 64..127 = @W1b.
// Theory: consumer kernels on other XCDs hit DIRTY lines in the writer's L2
// (slow probe+writeback path). nt-stores stream producer data to L3 clean.

#define D 128
#define HID 64

typedef __attribute__((ext_vector_type(8))) short short8;
typedef __attribute__((ext_vector_type(4))) float f32x4;
typedef __attribute__((ext_vector_type(4))) unsigned int uintv4;
typedef _Float16 h2 __attribute__((ext_vector_type(2)));

union U32H2 { unsigned u; h2 h; };

__device__ inline unsigned short f2bf(float f) {
    union { float f; unsigned int u; } x;
    x.f = f;
    unsigned int r = x.u + 0x7FFFu + ((x.u >> 16) & 1u);   // RNE
    return (unsigned short)(r >> 16);
}

// e5m2 = top byte of IEEE f16 (we control both encode and decode).
__device__ inline unsigned int f2e5u(float f) {        // returns byte in [0,255]
    _Float16 h = (_Float16)f;
    unsigned short u;
    __builtin_memcpy(&u, &h, 2);
    unsigned short r = (unsigned short)(u + 0x7Fu + ((u >> 8) & 1u));  // RNE to 8b
    return (unsigned int)(r >> 8) & 0xFFu;
}

__device__ inline unsigned packh(float lo, float hi) {
    _Float16 l = (_Float16)lo, h = (_Float16)hi;
    unsigned short ul, uh;
    __builtin_memcpy(&ul, &l, 2);
    __builtin_memcpy(&uh, &h, 2);
    return (unsigned)ul | ((unsigned)uh << 16);
}

__device__ inline h2 relu2(h2 x) {
#if __has_builtin(__builtin_elementwise_max)
    return __builtin_elementwise_max(x, (h2)((_Float16)0));
#else
    h2 r;
    r[0] = x[0] > (_Float16)0 ? x[0] : (_Float16)0;
    r[1] = x[1] > (_Float16)0 ? x[1] : (_Float16)0;
    return r;
#endif
}

__device__ inline float dot2acc(h2 a, h2 b, float c) {
#if __has_builtin(__builtin_amdgcn_fdot2)
    return __builtin_amdgcn_fdot2(a, b, c, false);
#else
    c = fmaf((float)a[0], (float)b[0], c);
    return fmaf((float)a[1], (float)b[1], c);
#endif
}

// --- prep: fragment-ordered W table (bf16) + per-r packed cnw table ---
// cnw[r*16 + q]     = f16pair cnode words   (q=0..7)  for lane-in-quad r
// cnw[r*16 + 8 + q] = f16pair W2 words
__global__ __launch_bounds__(256) void pg_prep(
    const float* __restrict__ embeds, const float* __restrict__ W1,
    const float* __restrict__ b1, const float* __restrict__ W2,
    const int* __restrict__ nidx,
    unsigned short* __restrict__ bfrag, unsigned* __restrict__ cnw)
{
    int t = threadIdx.x;
    if (blockIdx.x < 64) {
        int i    = blockIdx.x * 256 + t;
        int j    = i & 7;
        int lane = (i >> 3) & 63;
        int ct   = (i >> 9) & 7;
        int ks   = i >> 12;
        int k    = ks * 32 + (lane >> 4) * 8 + j;
        int col  = ct * 16 + (lane & 15);
        float w  = (col < HID) ? W1[k * HID + col]
                               : W1[(D + k) * HID + (col - HID)];
        __builtin_nontemporal_store(f2bf(w), bfrag + i);
    } else {
        __shared__ float cs[HID];
        if (t < HID) {
            int n = nidx[0];
            const float* nr = embeds + (size_t)n * D;
            float c = b1[t];
            #pragma unroll 8
            for (int k = 0; k < D; ++k)
                c = fmaf(nr[k], W1[(2 * D + k) * HID + t], c);
            cs[t] = c;
        }
        __syncthreads();
        if (t < 32) {
            int wi = t >> 1, sub = t & 1;          // pair index
            int j = 4 * wi + sub;                  // units (j, j+2)
            int r = t >> 3, q = t & 7;             // per-r layout
            __builtin_nontemporal_store(packh(cs[j], cs[j + 2]), cnw + r * 16 + q);
            __builtin_nontemporal_store(packh(W2[j], W2[j + 2]), cnw + r * 16 + 8 + q);
        }
    }
}

// --- node projections via MFMA: P[node][128] e5m2, barrier-free ---
__global__ __launch_bounds__(256) void pg_nodes(
    const float* __restrict__ embeds, const unsigned short* __restrict__ bfrag,
    unsigned char* __restrict__ P, int N, int NTILES)
{
    __shared__ unsigned char st[4][16 * 144];         // 9 KiB per-wave staging

    int wave  = threadIdx.x >> 6;
    int lane  = threadIdx.x & 63;
    int ntile = blockIdx.x * 4 + wave;
    if (ntile >= NTILES) return;

    int kg = lane >> 4;                               // 0..3 k-group
    int nr = ntile * 16 + (lane & 15);                // node (B-operand col)
    if (nr >= N) nr = N - 1;
    const float* row = embeds + (size_t)nr * D + kg * 8;

    short8 af[4];
    #pragma unroll
    for (int ks = 0; ks < 4; ++ks) {
        float4 v0 = *reinterpret_cast<const float4*>(row + ks * 32);
        float4 v1 = *reinterpret_cast<const float4*>(row + ks * 32 + 4);
        union { float f; unsigned u; } c[8];
        c[0].f = v0.x; c[1].f = v0.y; c[2].f = v0.z; c[3].f = v0.w;
        c[4].f = v1.x; c[5].f = v1.y; c[6].f = v1.z; c[7].f = v1.w;
        union { unsigned u[4]; short8 s; } pk;
        #pragma unroll
        for (int p = 0; p < 4; ++p)                   // truncate-pack 2 f32 -> u32
            pk.u[p] = (c[2 * p + 1].u & 0xFFFF0000u) | (c[2 * p].u >> 16);
        af[ks] = pk.s;
    }

    const short8* gw = reinterpret_cast<const short8*>(bfrag);

    f32x4 acc[8];
    #pragma unroll
    for (int ct = 0; ct < 8; ++ct) acc[ct] = (f32x4){0.f, 0.f, 0.f, 0.f};

    // SWAPPED operands: D = W^T_tile * emb^T_tile -> D[wcol][node]
    #pragma unroll
    for (int ct = 0; ct < 8; ++ct) {
        #pragma unroll
        for (int ks = 0; ks < 4; ++ks) {
            short8 wf = gw[(ks * 8 + ct) * 64 + lane];
            acc[ct] = __builtin_amdgcn_mfma_f32_16x16x32_bf16(wf, af[ks], acc[ct], 0, 0, 0);
        }
    }

    // lane holds: node = lane&15, wcols = ct*16 + kg*4 + r (r=0..3 consecutive)
    #pragma unroll
    for (int ct = 0; ct < 8; ++ct) {
        unsigned w = f2e5u(acc[ct][0])
                   | (f2e5u(acc[ct][1]) << 8)
                   | (f2e5u(acc[ct][2]) << 16)
                   | (f2e5u(acc[ct][3]) << 24);
        *reinterpret_cast<unsigned*>(&st[wave][(lane & 15) * 144 + ct * 16 + kg * 4]) = w;
    }
    // same-wave LDS RAW -> compiler inserts lgkmcnt wait; no barrier needed
    #pragma unroll
    for (int h = 0; h < 2; ++h) {
        int c   = lane + h * 64;
        int r   = c >> 3;                              // 0..15
        int off = (c & 7) * 16;                        // 0..112
        uintv4 v = *reinterpret_cast<const uintv4*>(&st[wave][r * 144 + off]);
        int node = ntile * 16 + r;
        if (node < N)
            __builtin_nontemporal_store(v,
                reinterpret_cast<uintv4*>(P + (size_t)node * 128 + off));
    }
}

// 16-unit partial MLP (lane covers units 16r..16r+15); no bias here.
__device__ inline float mlp16(uintv4 A, uintv4 B,
                              const unsigned* cn, const unsigned* w2)
{
    float sw = 0.f;
    #pragma unroll
    for (int w = 0; w < 4; ++w) {
        U32H2 a0, a1, b0, b1, c0, c1, W0, W1v;
        a0.u = (A[w] << 8) & 0xFF00FF00u;
        a1.u =  A[w]       & 0xFF00FF00u;
        b0.u = (B[w] << 8) & 0xFF00FF00u;
        b1.u =  B[w]       & 0xFF00FF00u;
        c0.u = cn[2 * w];  c1.u = cn[2 * w + 1];
        W0.u = w2[2 * w];  W1v.u = w2[2 * w + 1];
        h2 h0 = relu2(a0.h + b0.h + c0.h);
        h2 h1 = relu2(a1.h + b1.h + c1.h);
        sw = dot2acc(h0, W0.h, sw);
        sw = dot2acc(h1, W1v.h, sw);
    }
    return sw;
}

__device__ inline float gumbel_sigmoid(float uu, float sw) {
    float a = 0.9999f - 0.9998f * uu;                  // eps
    float b = 0.0001f + 0.9998f * uu;                  // 1-eps
    float gate = __logf(__fdividef(a, b));
    float x = (gate + sw) * 0.2f;                      // / TEMP
    return __fdividef(1.f, 1.f + __expf(-x));
}

// --- per-edge: quad (4 lanes) per edge, 2 edges per quad ---
__global__ __launch_bounds__(256) void pg_edge(
    const unsigned char* __restrict__ P, const uintv4* __restrict__ cnw4,
    const float* __restrict__ b2, const float* __restrict__ u,
    const int* __restrict__ src, const int* __restrict__ dst,
    float* __restrict__ out, int E)
{
    int r    = threadIdx.x & 3;                        // lane-in-quad
    int quad = (blockIdx.x * 256 + threadIdx.x) >> 2;  // global quad
    int e0   = quad * 2;
    if (e0 >= E) return;
    bool two = (e0 + 1 < E);

    // constants: one 64B line per lane (4x uint4, broadcast within r-group)
    uintv4 c0 = cnw4[r * 4 + 0], c1 = cnw4[r * 4 + 1];
    uintv4 c2 = cnw4[r * 4 + 2], c3 = cnw4[r * 4 + 3];
    unsigned cn[8] = {c0[0], c0[1], c0[2], c0[3], c1[0], c1[1], c1[2], c1[3]};
    unsigned w2[8] = {c2[0], c2[1], c2[2], c2[3], c3[0], c3[1], c3[2], c3[3]};

    int2 sv, dv;
    if (two) {
        sv = *reinterpret_cast<const int2*>(src + e0);   // uniform in quad
        dv = *reinterpret_cast<const int2*>(dst + e0);
    } else {
        sv.x = sv.y = src[e0];
        dv.x = dv.y = dst[e0];
    }

    // quad-cooperative row loads: lanes r=0..3 -> consecutive 16B chunks
    uintv4 A0 = *reinterpret_cast<const uintv4*>(P + (size_t)sv.x * 128 + r * 16);
    uintv4 B0 = *reinterpret_cast<const uintv4*>(P + (size_t)dv.x * 128 + 64 + r * 16);
    uintv4 A1 = *reinterpret_cast<const uintv4*>(P + (size_t)sv.y * 128 + r * 16);
    uintv4 B1 = *reinterpret_cast<const uintv4*>(P + (size_t)dv.y * 128 + 64 + r * 16);

    float sw0 = mlp16(A0, B0, cn, w2);
    float sw1 = mlp16(A1, B1, cn, w2);

    // quad reduce (masks 1,2 stay within the quad)
    sw0 += __shfl_xor(sw0, 1); sw0 += __shfl_xor(sw0, 2);
    sw1 += __shfl_xor(sw1, 1); sw1 += __shfl_xor(sw1, 2);

    if (r == 0) {
        float bb = b2[0];
        if (two) {
            float2 uv = *reinterpret_cast<const float2*>(u + e0);
            float2 o;
            o.x = gumbel_sigmoid(uv.x, sw0 + bb);
            o.y = gumbel_sigmoid(uv.y, sw1 + bb);
            *reinterpret_cast<float2*>(out + e0) = o;
        } else {
            out[e0] = gumbel_sigmoid(u[e0], sw0 + bb);
        }
    }
}

extern "C" void kernel_launch(void* const* d_in, const int* in_sizes, int n_in,
                              void* d_out, int out_size, void* d_ws, size_t ws_size,
                              hipStream_t stream) {
    const float* embeds = (const float*)d_in[0];
    const float* W1     = (const float*)d_in[1];
    const float* b1     = (const float*)d_in[2];
    const float* W2     = (const float*)d_in[3];
    const float* b2     = (const float*)d_in[4];
    const float* u      = (const float*)d_in[5];
    const int*   src    = (const int*)d_in[6];
    const int*   dst    = (const int*)d_in[7];
    const int*   nidx   = (const int*)d_in[8];

    int E = in_sizes[6];
    int N = in_sizes[0] / D;
    int NTILES = (N + 15) / 16;

    // ws: bfrag 16384 bf16 (32KB) | cnw 64 u32 (256B) | P [N][128] u8 (6.4MB)
    unsigned short* bfrag = (unsigned short*)d_ws;
    unsigned* cnw = (unsigned*)(bfrag + 16384);
    unsigned char* P = (unsigned char*)(cnw + 64);

    pg_prep<<<65, 256, 0, stream>>>(embeds, W1, b1, W2, nidx, bfrag, cnw);
    pg_nodes<<<(NTILES + 3) / 4, 256, 0, stream>>>(embeds, bfrag, P, N, NTILES);

    // quad (4 lanes) per edge, 2 edges per quad
    long quads = ((long)E + 1) / 2;
    int blocks = (int)((quads * 4 + 255) / 256);
    pg_edge<<<blocks, 256, 0, stream>>>(P, (const uintv4*)cnw, b2, u,
                                        src, dst, (float*)d_out, E);
}